// Round 10
// baseline (161.520 us; speedup 1.0000x reference)
//
#include <hip/hip_runtime.h>
#include <hip/hip_bf16.h>
#include <math.h>

#define DD 1024          // D (in == out features)
#define BT 8192          // B*N tokens
#define TWO_PI 6.28318530717958647692f

typedef float f32x4 __attribute__((ext_vector_type(4)));
typedef short bf16x8 __attribute__((ext_vector_type(8)));
typedef unsigned short u16x8 __attribute__((ext_vector_type(8)));
typedef unsigned short u16x4 __attribute__((ext_vector_type(4)));
typedef const __attribute__((address_space(1))) void g_void;
typedef __attribute__((address_space(3))) void l_void;

__device__ __forceinline__ unsigned short f2bf(float f) {
  unsigned int u = __float_as_uint(f);
  unsigned int r = (u + 0x7FFFu + ((u >> 16) & 1u)) >> 16;   // RNE
  return (unsigned short)r;
}

// ---------------------------------------------------------------------------
// build_G: G[k,m] = sum_o W[k,o] e^{+2pi i o m / D}; W sparsity is top-10 per
// k-ROW, so rows are read coalesced and ballot-compacted (deterministic,
// column order). Output Gt bf16 m-major: Gt[m][k] = ReG, Gt[m][1024+k] = ImG.
// Grid (8 m-tiles of 128, 16 k-ranges of 64), 256 threads.
// ---------------------------------------------------------------------------
__global__ __launch_bounds__(256) void build_G_kernel(
    const float* __restrict__ Wr, const float* __restrict__ Wi,
    unsigned short* __restrict__ Gt) {
  __shared__ float2 tw[DD];
  __shared__ int    cntA[64];
  __shared__ int    oA[64][24];
  __shared__ float  wrA[64][24];
  __shared__ float  wiA[64][24];
  const int tid = threadIdx.x, wave = tid >> 6, lane = tid & 63;
  const int mt = blockIdx.x;           // m-tile (0..7)
  const int ks = blockIdx.y;           // k-range (0..15)
  const int kbase = ks * 64;

  for (int j = tid; j < DD; j += 256) {
    float s, c;
    sincosf((TWO_PI / DD) * (float)j, &s, &c);
    tw[j] = make_float2(c, s);
  }
  // wave-parallel ballot compaction: wave handles rows kbase+wave*16..+15
  for (int rr = 0; rr < 16; ++rr) {
    int kl = wave * 16 + rr;
    int k  = kbase + kl;
    int cnt = 0;
    for (int cc = 0; cc < 16; ++cc) {
      int o = cc * 64 + lane;
      float wr = Wr[(size_t)k * DD + o];
      float wi = Wi[(size_t)k * DD + o];
      bool nz = (wr != 0.f) || (wi != 0.f);
      unsigned long long mk = __ballot(nz);
      if (nz) {
        int pos = cnt + (int)__popcll(mk & ((1ull << lane) - 1ull));
        if (pos < 24) { oA[kl][pos] = o; wrA[kl][pos] = wr; wiA[kl][pos] = wi; }
      }
      cnt += (int)__popcll(mk);
    }
    if (lane == 0) cntA[kl] = cnt > 24 ? 24 : cnt;
  }
  __syncthreads();

  const int ml = tid >> 1;             // 0..127
  const int kh = tid & 1;              // k-half of the 64
  const int m  = mt * 128 + ml;
  float gre[32], gim[32];
#pragma unroll
  for (int q = 0; q < 32; q++) { gre[q] = 0.f; gim[q] = 0.f; }
#pragma unroll
  for (int q = 0; q < 32; q++) {
    int kl = kh * 32 + q;
    int n  = cntA[kl];
    for (int j = 0; j < n; ++j) {
      int   o  = oA[kl][j];
      float wr = wrA[kl][j];
      float wi = wiA[kl][j];
      float2 cs = tw[(m * o) & (DD - 1)];   // e^{+i th} = (c, s)
      gre[q] += wr * cs.x - wi * cs.y;
      gim[q] += wr * cs.y + wi * cs.x;
    }
  }
  size_t base = (size_t)m * 2048 + kbase + kh * 32;
#pragma unroll
  for (int v = 0; v < 4; v++) {
    u16x8 a, b;
#pragma unroll
    for (int q = 0; q < 8; q++) { a[q] = f2bf(gre[v * 8 + q]); b[q] = f2bf(gim[v * 8 + q]); }
    *(u16x8*)(Gt + base + v * 8)        = a;
    *(u16x8*)(Gt + base + 1024 + v * 8) = b;
  }
}

// ---------------------------------------------------------------------------
// build_M: P_z[m][d] = sum_{K in z-chunk} Gt[m][K] * B(d,K),
// B(d,K) = cos(2pi K d/D) for K<1024, sin(2pi (K-1024) d/D) for K>=1024
// (note (K-1024)*d = K*d mod 1024). M = (1/D) * sum_z P_z done in reduce.
// A staged via global_load_lds; B generated in-register (__sincosf) +
// ds_write (R7-proven pattern). 128x128, BK=32, 4 waves, split-K x4.
// ---------------------------------------------------------------------------
__global__ __launch_bounds__(256) void build_M_kernel(
    const unsigned short* __restrict__ Gt,   // (1024 x 2048) bf16, m-major
    float* __restrict__ P, int kLen) {
  __shared__ __align__(16) unsigned short Asm[128 * 32];
  __shared__ __align__(16) unsigned short Bsm[128 * 32];
  const int tid  = threadIdx.x;
  const int wave = tid >> 6, lane = tid & 63;
  const int wr = wave >> 1, wc = wave & 1;
  const int row0 = blockIdx.y * 128;     // m
  const int col0 = blockIdx.x * 128;     // d
  const int kBeg = blockIdx.z * kLen;

  f32x4 acc[4][4] = {};

  for (int k0 = kBeg; k0 < kBeg + kLen; k0 += 32) {
    __syncthreads();
#pragma unroll
    for (int is = 0; is < 2; is++) {     // A = Gt rows (m-major)
      int e = is * 256 + tid;
      int r = e >> 2, c = (e & 3) * 8;
      const unsigned short* ga = Gt + (size_t)(row0 + r) * 2048 + k0 + c;
      __builtin_amdgcn_global_load_lds((g_void*)ga,
          (l_void*)(Asm + is * 2048 + wave * 512), 16, 0, 0);
    }
#pragma unroll
    for (int is = 0; is < 2; is++) {     // B = generated twiddles
      int e = is * 256 + tid;
      int r = e >> 2, c = (e & 3) * 8;
      int d = col0 + r;
      u16x8 v;
#pragma unroll
      for (int q = 0; q < 8; q++) {
        int K   = k0 + c + q;
        int idx = (K * d) & (DD - 1);
        float s, cc;
        __sincosf((TWO_PI / DD) * (float)idx, &s, &cc);
        v[q] = f2bf((K < DD) ? cc : s);
      }
      *(u16x8*)(Bsm + e * 8) = v;
    }
    __syncthreads();

    bf16x8 af[4], bfr[4];
#pragma unroll
    for (int i = 0; i < 4; i++) {
      int ra = wr * 64 + i * 16 + (lane & 15);
      af[i]  = *(const bf16x8*)&Asm[ra * 32 + (lane >> 4) * 8];
      int rb = wc * 64 + i * 16 + (lane & 15);
      bfr[i] = *(const bf16x8*)&Bsm[rb * 32 + (lane >> 4) * 8];
    }
#pragma unroll
    for (int i = 0; i < 4; i++)
#pragma unroll
      for (int j = 0; j < 4; j++)
        acc[i][j] = __builtin_amdgcn_mfma_f32_16x16x32_bf16(af[i], bfr[j], acc[i][j], 0, 0, 0);
  }

  const int crow0 = row0 + wr * 64;
  const int ccol0 = col0 + wc * 64;
  float* O = P + (size_t)blockIdx.z * DD * DD;
#pragma unroll
  for (int i = 0; i < 4; i++)
#pragma unroll
    for (int j = 0; j < 4; j++) {
      int cc = ccol0 + j * 16 + (lane & 15);
#pragma unroll
      for (int v = 0; v < 4; v++) {
        int rr = crow0 + i * 16 + (lane >> 4) * 4 + v;
        O[(size_t)rr * DD + cc] = acc[i][j][v];
      }
    }
}

// ---------------------------------------------------------------------------
// Fused: blocks [0,1024): Mb[i] = bf16(sum_z P_z[i]/D) (x4 vec);
//        blocks [1024,5120): Xb = bf16(x) (x8 vec).  One launch, two jobs.
// ---------------------------------------------------------------------------
__global__ __launch_bounds__(256) void reduce_convert_kernel(
    const float* __restrict__ P, unsigned short* __restrict__ Mb,
    const float* __restrict__ X, unsigned short* __restrict__ Xb) {
  const int b = blockIdx.x;
  if (b < 1024) {
    const size_t NE = (size_t)DD * DD;
    size_t i = ((size_t)b * 256 + threadIdx.x) * 4;
    float4 s = *(const float4*)(P + i);
#pragma unroll
    for (int z = 1; z < 4; z++) {
      float4 p = *(const float4*)(P + z * NE + i);
      s.x += p.x; s.y += p.y; s.z += p.z; s.w += p.w;
    }
    const float inv = 1.0f / (float)DD;
    u16x4 v;
    v[0] = f2bf(s.x * inv); v[1] = f2bf(s.y * inv);
    v[2] = f2bf(s.z * inv); v[3] = f2bf(s.w * inv);
    *(u16x4*)(Mb + i) = v;
  } else {
    size_t i = (size_t)(b - 1024) * 256 + threadIdx.x;   // chunk of 8
    const float4* p = (const float4*)(X + i * 8);
    float4 a = p[0], c = p[1];
    u16x8 v;
    v[0] = f2bf(a.x); v[1] = f2bf(a.y); v[2] = f2bf(a.z); v[3] = f2bf(a.w);
    v[4] = f2bf(c.x); v[5] = f2bf(c.y); v[6] = f2bf(c.z); v[7] = f2bf(c.w);
    *(u16x8*)(Xb + i * 8) = v;
  }
}

// ---------------------------------------------------------------------------
// gemm_y (R3-proven best): Y[t][m] = sum_d Xb[t][d]*Mb[m][d] + bias[m].
// 128x128 tile, 4 waves (2x2), BK=32, global_load_lds w16, 2-barrier loop.
// ---------------------------------------------------------------------------
__global__ __launch_bounds__(256) void gemm_y_kernel(
    const unsigned short* __restrict__ Xb,   // (8192 x 1024) bf16
    const unsigned short* __restrict__ Mb,   // (1024 x 1024) bf16
    const float* __restrict__ bias,
    float* __restrict__ Y) {
  __shared__ __align__(16) unsigned short Asm[128 * 32];
  __shared__ __align__(16) unsigned short Bsm[128 * 32];
  const int tid  = threadIdx.x;
  const int wave = tid >> 6, lane = tid & 63;
  const int wr = wave >> 1, wc = wave & 1;
  const int row0 = blockIdx.y * 128;
  const int col0 = blockIdx.x * 128;

  f32x4 acc[4][4] = {};

  for (int k0 = 0; k0 < DD; k0 += 32) {
    __syncthreads();
#pragma unroll
    for (int is = 0; is < 2; is++) {
      int e = is * 256 + tid;
      int r = e >> 2, c = (e & 3) * 8;
      const unsigned short* ga = Xb + (size_t)(row0 + r) * DD + k0 + c;
      const unsigned short* gb = Mb + (size_t)(col0 + r) * DD + k0 + c;
      __builtin_amdgcn_global_load_lds((g_void*)ga,
          (l_void*)(Asm + is * 2048 + wave * 512), 16, 0, 0);
      __builtin_amdgcn_global_load_lds((g_void*)gb,
          (l_void*)(Bsm + is * 2048 + wave * 512), 16, 0, 0);
    }
    __syncthreads();

    bf16x8 af[4], bfr[4];
#pragma unroll
    for (int i = 0; i < 4; i++) {
      int ra = wr * 64 + i * 16 + (lane & 15);
      af[i]  = *(const bf16x8*)&Asm[ra * 32 + (lane >> 4) * 8];
      int rb = wc * 64 + i * 16 + (lane & 15);
      bfr[i] = *(const bf16x8*)&Bsm[rb * 32 + (lane >> 4) * 8];
    }
#pragma unroll
    for (int i = 0; i < 4; i++)
#pragma unroll
      for (int j = 0; j < 4; j++)
        acc[i][j] = __builtin_amdgcn_mfma_f32_16x16x32_bf16(af[i], bfr[j], acc[i][j], 0, 0, 0);
  }

  const int crow0 = row0 + wr * 64;
  const int ccol0 = col0 + wc * 64;
  float bv[4];
#pragma unroll
  for (int j = 0; j < 4; j++)
    bv[j] = bias[ccol0 + j * 16 + (lane & 15)];
#pragma unroll
  for (int i = 0; i < 4; i++)
#pragma unroll
    for (int j = 0; j < 4; j++) {
      int cc = ccol0 + j * 16 + (lane & 15);
#pragma unroll
      for (int v = 0; v < 4; v++) {
        int rr = crow0 + i * 16 + (lane >> 4) * 4 + v;
        Y[(size_t)rr * DD + cc] = acc[i][j][v] + bv[j];
      }
    }
}

// ---------------------------------------------------------------------------
extern "C" void kernel_launch(void* const* d_in, const int* in_sizes, int n_in,
                              void* d_out, int out_size, void* d_ws, size_t ws_size,
                              hipStream_t stream) {
  const float* x    = (const float*)d_in[0];
  const float* wrp  = (const float*)d_in[1];
  const float* wip  = (const float*)d_in[2];
  const float* bias = (const float*)d_in[3];
  float*       y    = (float*)d_out;

  char* ws = (char*)d_ws;
  const size_t MB = 1024 * 1024;
  unsigned short* Gt = (unsigned short*)(ws + 0);        // 4 MB  [m][2048]
  unsigned short* Mb = (unsigned short*)(ws + 4 * MB);   // 2 MB  [m][d]
  float*          P  = (float*)(ws + 16 * MB);           // 16 MB (4 partials)
  unsigned short* Xb = (unsigned short*)(ws + 32 * MB);  // 16 MB

  // G[k,m] from sparse W rows (ballot compaction)
  build_G_kernel<<<dim3(8, 16), 256, 0, stream>>>(wrp, wip, Gt);
  // P[z] = Gt . B(twiddles)^T over K-chunk z of 512   (split-K x4)
  build_M_kernel<<<dim3(8, 8, 4), 256, 0, stream>>>(Gt, P, 512);
  // Mb = bf16(sum P / D)  and  Xb = bf16(x)   (one fused launch)
  reduce_convert_kernel<<<5120, 256, 0, stream>>>(P, Mb, x, Xb);
  // Y = Xb . Mb^T + bias
  gemm_y_kernel<<<dim3(8, 64), 256, 0, stream>>>(Xb, Mb, bias, y);
}

// Round 11
// 94.584 us; speedup vs baseline: 1.7077x; 1.7077x over previous
//
#include <hip/hip_runtime.h>
#include <hip/hip_bf16.h>
#include <math.h>

#define DD 1024          // D (in == out features)
#define BT 8192          // B*N tokens
#define TWO_PI 6.28318530717958647692f

typedef float f32x4 __attribute__((ext_vector_type(4)));
typedef short bf16x8 __attribute__((ext_vector_type(8)));
typedef unsigned short u16x8 __attribute__((ext_vector_type(8)));
typedef unsigned short u16x4 __attribute__((ext_vector_type(4)));
typedef const __attribute__((address_space(1))) void g_void;
typedef __attribute__((address_space(3))) void l_void;

__device__ __forceinline__ unsigned short f2bf(float f) {
  unsigned int u = __float_as_uint(f);
  unsigned int r = (u + 0x7FFFu + ((u >> 16) & 1u)) >> 16;   // RNE
  return (unsigned short)r;
}

// ---------------------------------------------------------------------------
// build_G (build_T-proven structure): G[k,m] = sum_o W[k,o] e^{+2pi i o m/D}.
// One block per k-row (1024 blocks). W's top-k sparsity is per ROW, so reads
// are coalesced directly from Wr/Wi — no transpose. Nonzeros compacted into
// LDS via Hillis-Steele scan (deterministic order), then each thread computes
// 4 m-values from the 1024-entry twiddle table. Coalesced float2 output
// Gf[k][m] = (Re, Im).
// ---------------------------------------------------------------------------
__global__ __launch_bounds__(256) void build_G_kernel(
    const float* __restrict__ Wr, const float* __restrict__ Wi,
    float2* __restrict__ Gf) {
  __shared__ float2 tw[DD];
  __shared__ int    oidx[64];
  __shared__ float2 wval[64];
  __shared__ int    sc[256];
  const int k = blockIdx.x, tid = threadIdx.x;

  for (int j = tid; j < DD; j += 256) {
    float s, c;
    sincosf((TWO_PI / DD) * (float)j, &s, &c);
    tw[j] = make_float2(c, s);
  }
  int cnt = 0;
  float2 wl[4];
  int    ol[4];
#pragma unroll
  for (int q = 0; q < 4; q++) {
    int o = tid + q * 256;
    float wr = Wr[(size_t)k * DD + o];
    float wi = Wi[(size_t)k * DD + o];
    if (wr != 0.f || wi != 0.f) { wl[cnt] = make_float2(wr, wi); ol[cnt] = o; cnt++; }
  }
  sc[tid] = cnt;
  __syncthreads();
#pragma unroll
  for (int dstep = 1; dstep < 256; dstep <<= 1) {
    int v = (tid >= dstep) ? sc[tid - dstep] : 0;
    __syncthreads();
    sc[tid] += v;
    __syncthreads();
  }
  int p = sc[tid] - cnt;
  for (int q = 0; q < cnt; q++) { oidx[p + q] = ol[q]; wval[p + q] = wl[q]; }
  __syncthreads();
  const int nnz = sc[255];
  for (int m = tid; m < DD; m += 256) {
    float re = 0.f, im = 0.f;
    for (int j = 0; j < nnz; j++) {
      int    o  = oidx[j];
      float2 w  = wval[j];
      float2 cs = tw[(o * m) & (DD - 1)];     // e^{+i th} = (c, s)
      re += w.x * cs.x - w.y * cs.y;
      im += w.x * cs.y + w.y * cs.x;
    }
    Gf[(size_t)k * DD + m] = make_float2(re, im);
  }
}

// ---------------------------------------------------------------------------
// transpose_G (proven tile transpose): Gt[m][k] = bf16(Re Gf[k][m]);
// Gt[m][1024+k] = bf16(Im Gf[k][m]).
// ---------------------------------------------------------------------------
__global__ __launch_bounds__(256) void transpose_G_kernel(
    const float2* __restrict__ Gf, unsigned short* __restrict__ Gt) {
  __shared__ float2 tile[64][65];
  const int k0 = blockIdx.x * 64, m0 = blockIdx.y * 64;
  for (int q = threadIdx.x; q < 64 * 64; q += 256) {
    int r = q >> 6, c = q & 63;                 // r: k, c: m
    tile[r][c] = Gf[(size_t)(k0 + r) * DD + m0 + c];
  }
  __syncthreads();
  for (int q = threadIdx.x; q < 64 * 64; q += 256) {
    int r = q >> 6, c = q & 63;                 // r: m, c: k
    float2 v = tile[c][r];
    Gt[(size_t)(m0 + r) * 2048 + k0 + c]        = f2bf(v.x);
    Gt[(size_t)(m0 + r) * 2048 + 1024 + k0 + c] = f2bf(v.y);
  }
}

// ---------------------------------------------------------------------------
// build_M: P_z[m][d] = sum_{K in z-chunk} Gt[m][K] * B(d,K),
// B(d,K) = cos(2pi K d/D) for K<1024, sin for K>=1024 ((K-1024)d = Kd mod D).
// A staged via global_load_lds; B generated in-register (__sincosf) +
// ds_write. 128x128, BK=32, 4 waves, split-K x4.
// ---------------------------------------------------------------------------
__global__ __launch_bounds__(256) void build_M_kernel(
    const unsigned short* __restrict__ Gt,   // (1024 x 2048) bf16, m-major
    float* __restrict__ P, int kLen) {
  __shared__ __align__(16) unsigned short Asm[128 * 32];
  __shared__ __align__(16) unsigned short Bsm[128 * 32];
  const int tid  = threadIdx.x;
  const int wave = tid >> 6, lane = tid & 63;
  const int wr = wave >> 1, wc = wave & 1;
  const int row0 = blockIdx.y * 128;     // m
  const int col0 = blockIdx.x * 128;     // d
  const int kBeg = blockIdx.z * kLen;

  f32x4 acc[4][4] = {};

  for (int k0 = kBeg; k0 < kBeg + kLen; k0 += 32) {
    __syncthreads();
#pragma unroll
    for (int is = 0; is < 2; is++) {     // A = Gt rows (m-major)
      int e = is * 256 + tid;
      int r = e >> 2, c = (e & 3) * 8;
      const unsigned short* ga = Gt + (size_t)(row0 + r) * 2048 + k0 + c;
      __builtin_amdgcn_global_load_lds((g_void*)ga,
          (l_void*)(Asm + is * 2048 + wave * 512), 16, 0, 0);
    }
#pragma unroll
    for (int is = 0; is < 2; is++) {     // B = generated twiddles
      int e = is * 256 + tid;
      int r = e >> 2, c = (e & 3) * 8;
      int d = col0 + r;
      u16x8 v;
#pragma unroll
      for (int q = 0; q < 8; q++) {
        int K   = k0 + c + q;
        int idx = (K * d) & (DD - 1);
        float s, cc;
        __sincosf((TWO_PI / DD) * (float)idx, &s, &cc);
        v[q] = f2bf((K < DD) ? cc : s);
      }
      *(u16x8*)(Bsm + e * 8) = v;
    }
    __syncthreads();

    bf16x8 af[4], bfr[4];
#pragma unroll
    for (int i = 0; i < 4; i++) {
      int ra = wr * 64 + i * 16 + (lane & 15);
      af[i]  = *(const bf16x8*)&Asm[ra * 32 + (lane >> 4) * 8];
      int rb = wc * 64 + i * 16 + (lane & 15);
      bfr[i] = *(const bf16x8*)&Bsm[rb * 32 + (lane >> 4) * 8];
    }
#pragma unroll
    for (int i = 0; i < 4; i++)
#pragma unroll
      for (int j = 0; j < 4; j++)
        acc[i][j] = __builtin_amdgcn_mfma_f32_16x16x32_bf16(af[i], bfr[j], acc[i][j], 0, 0, 0);
  }

  const int crow0 = row0 + wr * 64;
  const int ccol0 = col0 + wc * 64;
  float* O = P + (size_t)blockIdx.z * DD * DD;
#pragma unroll
  for (int i = 0; i < 4; i++)
#pragma unroll
    for (int j = 0; j < 4; j++) {
      int cc = ccol0 + j * 16 + (lane & 15);
#pragma unroll
      for (int v = 0; v < 4; v++) {
        int rr = crow0 + i * 16 + (lane >> 4) * 4 + v;
        O[(size_t)rr * DD + cc] = acc[i][j][v];
      }
    }
}

// ---------------------------------------------------------------------------
// Fused: blocks [0,1024): Mb[i] = bf16(sum_z P_z[i]/D) (x4 vec);
//        blocks [1024,5120): Xb = bf16(x) (x8 vec).  One launch, two jobs.
// ---------------------------------------------------------------------------
__global__ __launch_bounds__(256) void reduce_convert_kernel(
    const float* __restrict__ P, unsigned short* __restrict__ Mb,
    const float* __restrict__ X, unsigned short* __restrict__ Xb) {
  const int b = blockIdx.x;
  if (b < 1024) {
    const size_t NE = (size_t)DD * DD;
    size_t i = ((size_t)b * 256 + threadIdx.x) * 4;
    float4 s = *(const float4*)(P + i);
#pragma unroll
    for (int z = 1; z < 4; z++) {
      float4 p = *(const float4*)(P + z * NE + i);
      s.x += p.x; s.y += p.y; s.z += p.z; s.w += p.w;
    }
    const float inv = 1.0f / (float)DD;
    u16x4 v;
    v[0] = f2bf(s.x * inv); v[1] = f2bf(s.y * inv);
    v[2] = f2bf(s.z * inv); v[3] = f2bf(s.w * inv);
    *(u16x4*)(Mb + i) = v;
  } else {
    size_t i = (size_t)(b - 1024) * 256 + threadIdx.x;   // chunk of 8
    const float4* p = (const float4*)(X + i * 8);
    float4 a = p[0], c = p[1];
    u16x8 v;
    v[0] = f2bf(a.x); v[1] = f2bf(a.y); v[2] = f2bf(a.z); v[3] = f2bf(a.w);
    v[4] = f2bf(c.x); v[5] = f2bf(c.y); v[6] = f2bf(c.z); v[7] = f2bf(c.w);
    *(u16x8*)(Xb + i * 8) = v;
  }
}

// ---------------------------------------------------------------------------
// gemm_y (R3-proven best): Y[t][m] = sum_d Xb[t][d]*Mb[m][d] + bias[m].
// 128x128 tile, 4 waves (2x2), BK=32, global_load_lds w16, 2-barrier loop.
// ---------------------------------------------------------------------------
__global__ __launch_bounds__(256) void gemm_y_kernel(
    const unsigned short* __restrict__ Xb,   // (8192 x 1024) bf16
    const unsigned short* __restrict__ Mb,   // (1024 x 1024) bf16
    const float* __restrict__ bias,
    float* __restrict__ Y) {
  __shared__ __align__(16) unsigned short Asm[128 * 32];
  __shared__ __align__(16) unsigned short Bsm[128 * 32];
  const int tid  = threadIdx.x;
  const int wave = tid >> 6, lane = tid & 63;
  const int wr = wave >> 1, wc = wave & 1;
  const int row0 = blockIdx.y * 128;
  const int col0 = blockIdx.x * 128;

  f32x4 acc[4][4] = {};

  for (int k0 = 0; k0 < DD; k0 += 32) {
    __syncthreads();
#pragma unroll
    for (int is = 0; is < 2; is++) {
      int e = is * 256 + tid;
      int r = e >> 2, c = (e & 3) * 8;
      const unsigned short* ga = Xb + (size_t)(row0 + r) * DD + k0 + c;
      const unsigned short* gb = Mb + (size_t)(col0 + r) * DD + k0 + c;
      __builtin_amdgcn_global_load_lds((g_void*)ga,
          (l_void*)(Asm + is * 2048 + wave * 512), 16, 0, 0);
      __builtin_amdgcn_global_load_lds((g_void*)gb,
          (l_void*)(Bsm + is * 2048 + wave * 512), 16, 0, 0);
    }
    __syncthreads();

    bf16x8 af[4], bfr[4];
#pragma unroll
    for (int i = 0; i < 4; i++) {
      int ra = wr * 64 + i * 16 + (lane & 15);
      af[i]  = *(const bf16x8*)&Asm[ra * 32 + (lane >> 4) * 8];
      int rb = wc * 64 + i * 16 + (lane & 15);
      bfr[i] = *(const bf16x8*)&Bsm[rb * 32 + (lane >> 4) * 8];
    }
#pragma unroll
    for (int i = 0; i < 4; i++)
#pragma unroll
      for (int j = 0; j < 4; j++)
        acc[i][j] = __builtin_amdgcn_mfma_f32_16x16x32_bf16(af[i], bfr[j], acc[i][j], 0, 0, 0);
  }

  const int crow0 = row0 + wr * 64;
  const int ccol0 = col0 + wc * 64;
  float bv[4];
#pragma unroll
  for (int j = 0; j < 4; j++)
    bv[j] = bias[ccol0 + j * 16 + (lane & 15)];
#pragma unroll
  for (int i = 0; i < 4; i++)
#pragma unroll
    for (int j = 0; j < 4; j++) {
      int cc = ccol0 + j * 16 + (lane & 15);
#pragma unroll
      for (int v = 0; v < 4; v++) {
        int rr = crow0 + i * 16 + (lane >> 4) * 4 + v;
        Y[(size_t)rr * DD + cc] = acc[i][j][v] + bv[j];
      }
    }
}

// ---------------------------------------------------------------------------
extern "C" void kernel_launch(void* const* d_in, const int* in_sizes, int n_in,
                              void* d_out, int out_size, void* d_ws, size_t ws_size,
                              hipStream_t stream) {
  const float* x    = (const float*)d_in[0];
  const float* wrp  = (const float*)d_in[1];
  const float* wip  = (const float*)d_in[2];
  const float* bias = (const float*)d_in[3];
  float*       y    = (float*)d_out;

  char* ws = (char*)d_ws;
  const size_t MB = 1024 * 1024;
  float2*         Gf = (float2*)(ws + 0);                // 8 MB  [k][m]
  unsigned short* Gt = (unsigned short*)(ws + 8 * MB);   // 4 MB  [m][2048]
  unsigned short* Mb = (unsigned short*)(ws + 12 * MB);  // 2 MB  [m][d]
  float*          P  = (float*)(ws + 16 * MB);           // 16 MB (4 partials)
  unsigned short* Xb = (unsigned short*)(ws + 32 * MB);  // 16 MB

  // G[k,m] from sparse W rows (coalesced, scan compaction; 1024 blocks)
  build_G_kernel<<<DD, 256, 0, stream>>>(wrp, wip, Gf);
  // Gt[m][2048] bf16 (tile transpose)
  transpose_G_kernel<<<dim3(16, 16), 256, 0, stream>>>(Gf, Gt);
  // P[z] = Gt . B(twiddles)^T over K-chunk z of 512   (split-K x4)
  build_M_kernel<<<dim3(8, 8, 4), 256, 0, stream>>>(Gt, P, 512);
  // Mb = bf16(sum P / D)  and  Xb = bf16(x)   (one fused launch)
  reduce_convert_kernel<<<5120, 256, 0, stream>>>(P, Mb, x, Xb);
  // Y = Xb . Mb^T + bias
  gemm_y_kernel<<<dim3(8, 64), 256, 0, stream>>>(Xb, Mb, bias, y);
}

// Round 12
// 90.573 us; speedup vs baseline: 1.7833x; 1.0443x over previous
//
#include <hip/hip_runtime.h>
#include <hip/hip_bf16.h>
#include <math.h>

#define DD 1024          // D (in == out features)
#define BT 8192          // B*N tokens
#define TWO_PI 6.28318530717958647692f

typedef float f32x4 __attribute__((ext_vector_type(4)));
typedef short bf16x8 __attribute__((ext_vector_type(8)));
typedef unsigned short u16x8 __attribute__((ext_vector_type(8)));
typedef unsigned short u16x4 __attribute__((ext_vector_type(4)));
typedef const __attribute__((address_space(1))) void g_void;
typedef __attribute__((address_space(3))) void l_void;

__device__ __forceinline__ unsigned short f2bf(float f) {
  unsigned int u = __float_as_uint(f);
  unsigned int r = (u + 0x7FFFu + ((u >> 16) & 1u)) >> 16;   // RNE
  return (unsigned short)r;
}

// ---------------------------------------------------------------------------
// build_G: G[k,m] = sum_o W[k,o] e^{+2pi i o m/D}. One block per k-row;
// coalesced row reads (sparsity is per-row), scan compaction, twiddle table.
// ---------------------------------------------------------------------------
__global__ __launch_bounds__(256) void build_G_kernel(
    const float* __restrict__ Wr, const float* __restrict__ Wi,
    float2* __restrict__ Gf) {
  __shared__ float2 tw[DD];
  __shared__ int    oidx[64];
  __shared__ float2 wval[64];
  __shared__ int    sc[256];
  const int k = blockIdx.x, tid = threadIdx.x;

  for (int j = tid; j < DD; j += 256) {
    float s, c;
    sincosf((TWO_PI / DD) * (float)j, &s, &c);
    tw[j] = make_float2(c, s);
  }
  int cnt = 0;
  float2 wl[4];
  int    ol[4];
#pragma unroll
  for (int q = 0; q < 4; q++) {
    int o = tid + q * 256;
    float wr = Wr[(size_t)k * DD + o];
    float wi = Wi[(size_t)k * DD + o];
    if (wr != 0.f || wi != 0.f) { wl[cnt] = make_float2(wr, wi); ol[cnt] = o; cnt++; }
  }
  sc[tid] = cnt;
  __syncthreads();
#pragma unroll
  for (int dstep = 1; dstep < 256; dstep <<= 1) {
    int v = (tid >= dstep) ? sc[tid - dstep] : 0;
    __syncthreads();
    sc[tid] += v;
    __syncthreads();
  }
  int p = sc[tid] - cnt;
  for (int q = 0; q < cnt; q++) { oidx[p + q] = ol[q]; wval[p + q] = wl[q]; }
  __syncthreads();
  const int nnz = sc[255];
  for (int m = tid; m < DD; m += 256) {
    float re = 0.f, im = 0.f;
    for (int j = 0; j < nnz; j++) {
      int    o  = oidx[j];
      float2 w  = wval[j];
      float2 cs = tw[(o * m) & (DD - 1)];     // e^{+i th} = (c, s)
      re += w.x * cs.x - w.y * cs.y;
      im += w.x * cs.y + w.y * cs.x;
    }
    Gf[(size_t)k * DD + m] = make_float2(re, im);
  }
}

// ---------------------------------------------------------------------------
// transpose_G: Gt[m][k] = bf16(Re Gf[k][m]); Gt[m][1024+k] = bf16(Im).
// ---------------------------------------------------------------------------
__global__ __launch_bounds__(256) void transpose_G_kernel(
    const float2* __restrict__ Gf, unsigned short* __restrict__ Gt) {
  __shared__ float2 tile[64][65];
  const int k0 = blockIdx.x * 64, m0 = blockIdx.y * 64;
  for (int q = threadIdx.x; q < 64 * 64; q += 256) {
    int r = q >> 6, c = q & 63;                 // r: k, c: m
    tile[r][c] = Gf[(size_t)(k0 + r) * DD + m0 + c];
  }
  __syncthreads();
  for (int q = threadIdx.x; q < 64 * 64; q += 256) {
    int r = q >> 6, c = q & 63;                 // r: m, c: k
    float2 v = tile[c][r];
    Gt[(size_t)(m0 + r) * 2048 + k0 + c]        = f2bf(v.x);
    Gt[(size_t)(m0 + r) * 2048 + 1024 + k0 + c] = f2bf(v.y);
  }
}

// ---------------------------------------------------------------------------
// build_M: P_z[m][d] = sum_{K in z-chunk} Gt[m][K] * B(d,K),
// B(d,K) = cos(2pi K d/D) K<1024, sin otherwise. A via global_load_lds;
// B generated in-register (__sincosf) + ds_write. 128x128, BK=32, split-K x4.
// ---------------------------------------------------------------------------
__global__ __launch_bounds__(256) void build_M_kernel(
    const unsigned short* __restrict__ Gt,   // (1024 x 2048) bf16, m-major
    float* __restrict__ P, int kLen) {
  __shared__ __align__(16) unsigned short Asm[128 * 32];
  __shared__ __align__(16) unsigned short Bsm[128 * 32];
  const int tid  = threadIdx.x;
  const int wave = tid >> 6, lane = tid & 63;
  const int wr = wave >> 1, wc = wave & 1;
  const int row0 = blockIdx.y * 128;     // m
  const int col0 = blockIdx.x * 128;     // d
  const int kBeg = blockIdx.z * kLen;

  f32x4 acc[4][4] = {};

  for (int k0 = kBeg; k0 < kBeg + kLen; k0 += 32) {
    __syncthreads();
#pragma unroll
    for (int is = 0; is < 2; is++) {     // A = Gt rows (m-major)
      int e = is * 256 + tid;
      int r = e >> 2, c = (e & 3) * 8;
      const unsigned short* ga = Gt + (size_t)(row0 + r) * 2048 + k0 + c;
      __builtin_amdgcn_global_load_lds((g_void*)ga,
          (l_void*)(Asm + is * 2048 + wave * 512), 16, 0, 0);
    }
#pragma unroll
    for (int is = 0; is < 2; is++) {     // B = generated twiddles
      int e = is * 256 + tid;
      int r = e >> 2, c = (e & 3) * 8;
      int d = col0 + r;
      u16x8 v;
#pragma unroll
      for (int q = 0; q < 8; q++) {
        int K   = k0 + c + q;
        int idx = (K * d) & (DD - 1);
        float s, cc;
        __sincosf((TWO_PI / DD) * (float)idx, &s, &cc);
        v[q] = f2bf((K < DD) ? cc : s);
      }
      *(u16x8*)(Bsm + e * 8) = v;
    }
    __syncthreads();

    bf16x8 af[4], bfr[4];
#pragma unroll
    for (int i = 0; i < 4; i++) {
      int ra = wr * 64 + i * 16 + (lane & 15);
      af[i]  = *(const bf16x8*)&Asm[ra * 32 + (lane >> 4) * 8];
      int rb = wc * 64 + i * 16 + (lane & 15);
      bfr[i] = *(const bf16x8*)&Bsm[rb * 32 + (lane >> 4) * 8];
    }
#pragma unroll
    for (int i = 0; i < 4; i++)
#pragma unroll
      for (int j = 0; j < 4; j++)
        acc[i][j] = __builtin_amdgcn_mfma_f32_16x16x32_bf16(af[i], bfr[j], acc[i][j], 0, 0, 0);
  }

  const int crow0 = row0 + wr * 64;
  const int ccol0 = col0 + wc * 64;
  float* O = P + (size_t)blockIdx.z * DD * DD;
#pragma unroll
  for (int i = 0; i < 4; i++)
#pragma unroll
    for (int j = 0; j < 4; j++) {
      int cc = ccol0 + j * 16 + (lane & 15);
#pragma unroll
      for (int v = 0; v < 4; v++) {
        int rr = crow0 + i * 16 + (lane >> 4) * 4 + v;
        O[(size_t)rr * DD + cc] = acc[i][j][v];
      }
    }
}

// ---------------------------------------------------------------------------
// Fused: blocks [0,1024): Mb = bf16(sum_z P_z/D); [1024,5120): Xb = bf16(x).
// ---------------------------------------------------------------------------
__global__ __launch_bounds__(256) void reduce_convert_kernel(
    const float* __restrict__ P, unsigned short* __restrict__ Mb,
    const float* __restrict__ X, unsigned short* __restrict__ Xb) {
  const int b = blockIdx.x;
  if (b < 1024) {
    const size_t NE = (size_t)DD * DD;
    size_t i = ((size_t)b * 256 + threadIdx.x) * 4;
    float4 s = *(const float4*)(P + i);
#pragma unroll
    for (int z = 1; z < 4; z++) {
      float4 p = *(const float4*)(P + z * NE + i);
      s.x += p.x; s.y += p.y; s.z += p.z; s.w += p.w;
    }
    const float inv = 1.0f / (float)DD;
    u16x4 v;
    v[0] = f2bf(s.x * inv); v[1] = f2bf(s.y * inv);
    v[2] = f2bf(s.z * inv); v[3] = f2bf(s.w * inv);
    *(u16x4*)(Mb + i) = v;
  } else {
    size_t i = (size_t)(b - 1024) * 256 + threadIdx.x;   // chunk of 8
    const float4* p = (const float4*)(X + i * 8);
    float4 a = p[0], c = p[1];
    u16x8 v;
    v[0] = f2bf(a.x); v[1] = f2bf(a.y); v[2] = f2bf(a.z); v[3] = f2bf(a.w);
    v[4] = f2bf(c.x); v[5] = f2bf(c.y); v[6] = f2bf(c.z); v[7] = f2bf(c.w);
    *(u16x8*)(Xb + i * 8) = v;
  }
}

// ---------------------------------------------------------------------------
// gemm_y: Y[t][m] = sum_d Xb[t][d]*Mb[m][d] + bias[m].  128x128 tile,
// 4 waves, BK=32, global_load_lds w16, 2-barrier loop (R3-proven), PLUS
// chunked XCD swizzle (m192): 1-D grid 512; xcd = L&7 owns an 8x8 tile
// square (rows [xcd*8,+8), all 8 col-tiles) -> per-XCD L2 footprint drops
// 16.25 MB (col-panel streaming Xb) -> 4 MB (8 Xb panels + Mb resident).
// Sole change vs R11 (isolated A/B for the R4 confound).
// ---------------------------------------------------------------------------
__global__ __launch_bounds__(256) void gemm_y_kernel(
    const unsigned short* __restrict__ Xb,   // (8192 x 1024) bf16
    const unsigned short* __restrict__ Mb,   // (1024 x 1024) bf16
    const float* __restrict__ bias,
    float* __restrict__ Y) {
  __shared__ __align__(16) unsigned short Asm[128 * 32];
  __shared__ __align__(16) unsigned short Bsm[128 * 32];
  const int tid  = threadIdx.x;
  const int wave = tid >> 6, lane = tid & 63;
  const int wr = wave >> 1, wc = wave & 1;

  // chunked XCD swizzle: tile index w = (L%8)*64 + L/8; bx = w%8, by = w/8
  const int L  = blockIdx.x;
  const int w  = (L & 7) * 64 + (L >> 3);
  const int row0 = (w >> 3) * 128;
  const int col0 = (w & 7) * 128;

  f32x4 acc[4][4] = {};

  for (int k0 = 0; k0 < DD; k0 += 32) {
    __syncthreads();
#pragma unroll
    for (int is = 0; is < 2; is++) {
      int e = is * 256 + tid;
      int r = e >> 2, c = (e & 3) * 8;
      const unsigned short* ga = Xb + (size_t)(row0 + r) * DD + k0 + c;
      const unsigned short* gb = Mb + (size_t)(col0 + r) * DD + k0 + c;
      __builtin_amdgcn_global_load_lds((g_void*)ga,
          (l_void*)(Asm + is * 2048 + wave * 512), 16, 0, 0);
      __builtin_amdgcn_global_load_lds((g_void*)gb,
          (l_void*)(Bsm + is * 2048 + wave * 512), 16, 0, 0);
    }
    __syncthreads();

    bf16x8 af[4], bfr[4];
#pragma unroll
    for (int i = 0; i < 4; i++) {
      int ra = wr * 64 + i * 16 + (lane & 15);
      af[i]  = *(const bf16x8*)&Asm[ra * 32 + (lane >> 4) * 8];
      int rb = wc * 64 + i * 16 + (lane & 15);
      bfr[i] = *(const bf16x8*)&Bsm[rb * 32 + (lane >> 4) * 8];
    }
#pragma unroll
    for (int i = 0; i < 4; i++)
#pragma unroll
      for (int j = 0; j < 4; j++)
        acc[i][j] = __builtin_amdgcn_mfma_f32_16x16x32_bf16(af[i], bfr[j], acc[i][j], 0, 0, 0);
  }

  const int crow0 = row0 + wr * 64;
  const int ccol0 = col0 + wc * 64;
  float bv[4];
#pragma unroll
  for (int j = 0; j < 4; j++)
    bv[j] = bias[ccol0 + j * 16 + (lane & 15)];
#pragma unroll
  for (int i = 0; i < 4; i++)
#pragma unroll
    for (int j = 0; j < 4; j++) {
      int cc = ccol0 + j * 16 + (lane & 15);
#pragma unroll
      for (int v = 0; v < 4; v++) {
        int rr = crow0 + i * 16 + (lane >> 4) * 4 + v;
        Y[(size_t)rr * DD + cc] = acc[i][j][v] + bv[j];
      }
    }
}

// ---------------------------------------------------------------------------
extern "C" void kernel_launch(void* const* d_in, const int* in_sizes, int n_in,
                              void* d_out, int out_size, void* d_ws, size_t ws_size,
                              hipStream_t stream) {
  const float* x    = (const float*)d_in[0];
  const float* wrp  = (const float*)d_in[1];
  const float* wip  = (const float*)d_in[2];
  const float* bias = (const float*)d_in[3];
  float*       y    = (float*)d_out;

  char* ws = (char*)d_ws;
  const size_t MB = 1024 * 1024;
  float2*         Gf = (float2*)(ws + 0);                // 8 MB  [k][m]
  unsigned short* Gt = (unsigned short*)(ws + 8 * MB);   // 4 MB  [m][2048]
  unsigned short* Mb = (unsigned short*)(ws + 12 * MB);  // 2 MB  [m][d]
  float*          P  = (float*)(ws + 16 * MB);           // 16 MB (4 partials)
  unsigned short* Xb = (unsigned short*)(ws + 32 * MB);  // 16 MB

  build_G_kernel<<<DD, 256, 0, stream>>>(wrp, wip, Gf);
  transpose_G_kernel<<<dim3(16, 16), 256, 0, stream>>>(Gf, Gt);
  build_M_kernel<<<dim3(8, 8, 4), 256, 0, stream>>>(Gt, P, 512);
  reduce_convert_kernel<<<5120, 256, 0, stream>>>(P, Mb, x, Xb);
  // Y = Xb . Mb^T + bias   (XCD-chunk swizzled 1-D grid)
  gemm_y_kernel<<<512, 256, 0, stream>>>(Xb, Mb, bias, y);
}

// Round 13
// 87.533 us; speedup vs baseline: 1.8453x; 1.0347x over previous
//
#include <hip/hip_runtime.h>
#include <hip/hip_bf16.h>
#include <math.h>

#define DD 1024          // D (in == out features)
#define BT 8192          // B*N tokens
#define TWO_PI 6.28318530717958647692f

typedef float f32x4 __attribute__((ext_vector_type(4)));
typedef short bf16x8 __attribute__((ext_vector_type(8)));
typedef unsigned short u16x8 __attribute__((ext_vector_type(8)));
typedef unsigned short u16x4 __attribute__((ext_vector_type(4)));
typedef const __attribute__((address_space(1))) void g_void;
typedef __attribute__((address_space(3))) void l_void;

__device__ __forceinline__ unsigned short f2bf(float f) {
  unsigned int u = __float_as_uint(f);
  unsigned int r = (u + 0x7FFFu + ((u >> 16) & 1u)) >> 16;   // RNE
  return (unsigned short)r;
}

// ---------------------------------------------------------------------------
// build_G: G[k,m] = sum_o W[k,o] e^{+2pi i o m/D}. One block per k-row;
// coalesced row reads (sparsity is per-row), scan compaction, twiddle table.
// ---------------------------------------------------------------------------
__global__ __launch_bounds__(256) void build_G_kernel(
    const float* __restrict__ Wr, const float* __restrict__ Wi,
    float2* __restrict__ Gf) {
  __shared__ float2 tw[DD];
  __shared__ int    oidx[64];
  __shared__ float2 wval[64];
  __shared__ int    sc[256];
  const int k = blockIdx.x, tid = threadIdx.x;

  for (int j = tid; j < DD; j += 256) {
    float s, c;
    sincosf((TWO_PI / DD) * (float)j, &s, &c);
    tw[j] = make_float2(c, s);
  }
  int cnt = 0;
  float2 wl[4];
  int    ol[4];
#pragma unroll
  for (int q = 0; q < 4; q++) {
    int o = tid + q * 256;
    float wr = Wr[(size_t)k * DD + o];
    float wi = Wi[(size_t)k * DD + o];
    if (wr != 0.f || wi != 0.f) { wl[cnt] = make_float2(wr, wi); ol[cnt] = o; cnt++; }
  }
  sc[tid] = cnt;
  __syncthreads();
#pragma unroll
  for (int dstep = 1; dstep < 256; dstep <<= 1) {
    int v = (tid >= dstep) ? sc[tid - dstep] : 0;
    __syncthreads();
    sc[tid] += v;
    __syncthreads();
  }
  int p = sc[tid] - cnt;
  for (int q = 0; q < cnt; q++) { oidx[p + q] = ol[q]; wval[p + q] = wl[q]; }
  __syncthreads();
  const int nnz = sc[255];
  for (int m = tid; m < DD; m += 256) {
    float re = 0.f, im = 0.f;
    for (int j = 0; j < nnz; j++) {
      int    o  = oidx[j];
      float2 w  = wval[j];
      float2 cs = tw[(o * m) & (DD - 1)];     // e^{+i th} = (c, s)
      re += w.x * cs.x - w.y * cs.y;
      im += w.x * cs.y + w.y * cs.x;
    }
    Gf[(size_t)k * DD + m] = make_float2(re, im);
  }
}

// ---------------------------------------------------------------------------
// transpose_G: Gt[m][k] = bf16(Re Gf[k][m]); Gt[m][1024+k] = bf16(Im).
// ---------------------------------------------------------------------------
__global__ __launch_bounds__(256) void transpose_G_kernel(
    const float2* __restrict__ Gf, unsigned short* __restrict__ Gt) {
  __shared__ float2 tile[64][65];
  const int k0 = blockIdx.x * 64, m0 = blockIdx.y * 64;
  for (int q = threadIdx.x; q < 64 * 64; q += 256) {
    int r = q >> 6, c = q & 63;                 // r: k, c: m
    tile[r][c] = Gf[(size_t)(k0 + r) * DD + m0 + c];
  }
  __syncthreads();
  for (int q = threadIdx.x; q < 64 * 64; q += 256) {
    int r = q >> 6, c = q & 63;                 // r: m, c: k
    float2 v = tile[c][r];
    Gt[(size_t)(m0 + r) * 2048 + k0 + c]        = f2bf(v.x);
    Gt[(size_t)(m0 + r) * 2048 + 1024 + k0 + c] = f2bf(v.y);
  }
}

// ---------------------------------------------------------------------------
// build_M + convert_x fused launch (independent jobs, one dispatch):
// blocks [0,256): P_z[m][d] = sum_{K in z-chunk} Gt[m][K] * B(d,K)
//   (B(d,K) = cos(2pi K d/D) K<1024, sin otherwise; generated in-register;
//    A via global_load_lds; 128x128, BK=32, split-K x4). Compute-bound.
// blocks [256,4352): Xb = bf16(x), 8 elems/thread. Memory-bound — streams
//   under the MFMA blocks' compute, removing a serial memory phase.
// ---------------------------------------------------------------------------
__global__ __launch_bounds__(256) void build_M_convert_kernel(
    const unsigned short* __restrict__ Gt,   // (1024 x 2048) bf16, m-major
    float* __restrict__ P,
    const float* __restrict__ X, unsigned short* __restrict__ Xb) {
  __shared__ __align__(16) unsigned short Asm[128 * 32];
  __shared__ __align__(16) unsigned short Bsm[128 * 32];
  const int tid = threadIdx.x;

  if (blockIdx.x >= 256) {                 // ---- convert_x part ----
    size_t i = (size_t)(blockIdx.x - 256) * 256 + tid;   // chunk of 8
    const float4* p = (const float4*)(X + i * 8);
    float4 a = p[0], c = p[1];
    u16x8 v;
    v[0] = f2bf(a.x); v[1] = f2bf(a.y); v[2] = f2bf(a.z); v[3] = f2bf(a.w);
    v[4] = f2bf(c.x); v[5] = f2bf(c.y); v[6] = f2bf(c.z); v[7] = f2bf(c.w);
    *(u16x8*)(Xb + i * 8) = v;
    return;
  }

  // ---- build_M part: decompose 256 = (d-tile 8) x (m-tile 8) x (z 4) ----
  const int wave = tid >> 6, lane = tid & 63;
  const int wr = wave >> 1, wc = wave & 1;
  const int col0 = (blockIdx.x & 7) * 128;         // d
  const int row0 = ((blockIdx.x >> 3) & 7) * 128;  // m
  const int bz   = blockIdx.x >> 6;                // k-chunk
  const int kBeg = bz * 512;

  f32x4 acc[4][4] = {};

  for (int k0 = kBeg; k0 < kBeg + 512; k0 += 32) {
    __syncthreads();
#pragma unroll
    for (int is = 0; is < 2; is++) {     // A = Gt rows (m-major)
      int e = is * 256 + tid;
      int r = e >> 2, c = (e & 3) * 8;
      const unsigned short* ga = Gt + (size_t)(row0 + r) * 2048 + k0 + c;
      __builtin_amdgcn_global_load_lds((g_void*)ga,
          (l_void*)(Asm + is * 2048 + wave * 512), 16, 0, 0);
    }
#pragma unroll
    for (int is = 0; is < 2; is++) {     // B = generated twiddles
      int e = is * 256 + tid;
      int r = e >> 2, c = (e & 3) * 8;
      int d = col0 + r;
      u16x8 v;
#pragma unroll
      for (int q = 0; q < 8; q++) {
        int K   = k0 + c + q;
        int idx = (K * d) & (DD - 1);
        float s, cc;
        __sincosf((TWO_PI / DD) * (float)idx, &s, &cc);
        v[q] = f2bf((K < DD) ? cc : s);
      }
      *(u16x8*)(Bsm + e * 8) = v;
    }
    __syncthreads();

    bf16x8 af[4], bfr[4];
#pragma unroll
    for (int i = 0; i < 4; i++) {
      int ra = wr * 64 + i * 16 + (lane & 15);
      af[i]  = *(const bf16x8*)&Asm[ra * 32 + (lane >> 4) * 8];
      int rb = wc * 64 + i * 16 + (lane & 15);
      bfr[i] = *(const bf16x8*)&Bsm[rb * 32 + (lane >> 4) * 8];
    }
#pragma unroll
    for (int i = 0; i < 4; i++)
#pragma unroll
      for (int j = 0; j < 4; j++)
        acc[i][j] = __builtin_amdgcn_mfma_f32_16x16x32_bf16(af[i], bfr[j], acc[i][j], 0, 0, 0);
  }

  const int crow0 = row0 + wr * 64;
  const int ccol0 = col0 + wc * 64;
  float* O = P + (size_t)bz * DD * DD;
#pragma unroll
  for (int i = 0; i < 4; i++)
#pragma unroll
    for (int j = 0; j < 4; j++) {
      int cc = ccol0 + j * 16 + (lane & 15);
#pragma unroll
      for (int v = 0; v < 4; v++) {
        int rr = crow0 + i * 16 + (lane >> 4) * 4 + v;
        O[(size_t)rr * DD + cc] = acc[i][j][v];
      }
    }
}

// ---------------------------------------------------------------------------
// reduce_M: Mb[i] = bf16( sum_z P_z[i] / D ),  x4 vectorized, 4 partials.
// ---------------------------------------------------------------------------
__global__ __launch_bounds__(256) void reduce_M_kernel(
    const float* __restrict__ P, unsigned short* __restrict__ Mb) {
  const size_t NE = (size_t)DD * DD;
  size_t i = ((size_t)blockIdx.x * 256 + threadIdx.x) * 4;
  float4 s = *(const float4*)(P + i);
#pragma unroll
  for (int z = 1; z < 4; z++) {
    float4 p = *(const float4*)(P + z * NE + i);
    s.x += p.x; s.y += p.y; s.z += p.z; s.w += p.w;
  }
  const float inv = 1.0f / (float)DD;
  u16x4 v;
  v[0] = f2bf(s.x * inv); v[1] = f2bf(s.y * inv);
  v[2] = f2bf(s.z * inv); v[3] = f2bf(s.w * inv);
  *(u16x4*)(Mb + i) = v;
}

// ---------------------------------------------------------------------------
// gemm_y (R12-proven): 128x128 tile, 4 waves, BK=32, gload_lds w16,
// 2-barrier loop + chunked XCD swizzle (xcd = L&7 owns an 8x8 tile square).
// ---------------------------------------------------------------------------
__global__ __launch_bounds__(256) void gemm_y_kernel(
    const unsigned short* __restrict__ Xb,   // (8192 x 1024) bf16
    const unsigned short* __restrict__ Mb,   // (1024 x 1024) bf16
    const float* __restrict__ bias,
    float* __restrict__ Y) {
  __shared__ __align__(16) unsigned short Asm[128 * 32];
  __shared__ __align__(16) unsigned short Bsm[128 * 32];
  const int tid  = threadIdx.x;
  const int wave = tid >> 6, lane = tid & 63;
  const int wr = wave >> 1, wc = wave & 1;

  const int L  = blockIdx.x;
  const int w  = (L & 7) * 64 + (L >> 3);
  const int row0 = (w >> 3) * 128;
  const int col0 = (w & 7) * 128;

  f32x4 acc[4][4] = {};

  for (int k0 = 0; k0 < DD; k0 += 32) {
    __syncthreads();
#pragma unroll
    for (int is = 0; is < 2; is++) {
      int e = is * 256 + tid;
      int r = e >> 2, c = (e & 3) * 8;
      const unsigned short* ga = Xb + (size_t)(row0 + r) * DD + k0 + c;
      const unsigned short* gb = Mb + (size_t)(col0 + r) * DD + k0 + c;
      __builtin_amdgcn_global_load_lds((g_void*)ga,
          (l_void*)(Asm + is * 2048 + wave * 512), 16, 0, 0);
      __builtin_amdgcn_global_load_lds((g_void*)gb,
          (l_void*)(Bsm + is * 2048 + wave * 512), 16, 0, 0);
    }
    __syncthreads();

    bf16x8 af[4], bfr[4];
#pragma unroll
    for (int i = 0; i < 4; i++) {
      int ra = wr * 64 + i * 16 + (lane & 15);
      af[i]  = *(const bf16x8*)&Asm[ra * 32 + (lane >> 4) * 8];
      int rb = wc * 64 + i * 16 + (lane & 15);
      bfr[i] = *(const bf16x8*)&Bsm[rb * 32 + (lane >> 4) * 8];
    }
#pragma unroll
    for (int i = 0; i < 4; i++)
#pragma unroll
      for (int j = 0; j < 4; j++)
        acc[i][j] = __builtin_amdgcn_mfma_f32_16x16x32_bf16(af[i], bfr[j], acc[i][j], 0, 0, 0);
  }

  const int crow0 = row0 + wr * 64;
  const int ccol0 = col0 + wc * 64;
  float bv[4];
#pragma unroll
  for (int j = 0; j < 4; j++)
    bv[j] = bias[ccol0 + j * 16 + (lane & 15)];
#pragma unroll
  for (int i = 0; i < 4; i++)
#pragma unroll
    for (int j = 0; j < 4; j++) {
      int cc = ccol0 + j * 16 + (lane & 15);
#pragma unroll
      for (int v = 0; v < 4; v++) {
        int rr = crow0 + i * 16 + (lane >> 4) * 4 + v;
        Y[(size_t)rr * DD + cc] = acc[i][j][v] + bv[j];
      }
    }
}

// ---------------------------------------------------------------------------
extern "C" void kernel_launch(void* const* d_in, const int* in_sizes, int n_in,
                              void* d_out, int out_size, void* d_ws, size_t ws_size,
                              hipStream_t stream) {
  const float* x    = (const float*)d_in[0];
  const float* wrp  = (const float*)d_in[1];
  const float* wip  = (const float*)d_in[2];
  const float* bias = (const float*)d_in[3];
  float*       y    = (float*)d_out;

  char* ws = (char*)d_ws;
  const size_t MB = 1024 * 1024;
  float2*         Gf = (float2*)(ws + 0);                // 8 MB  [k][m]
  unsigned short* Gt = (unsigned short*)(ws + 8 * MB);   // 4 MB  [m][2048]
  unsigned short* Mb = (unsigned short*)(ws + 12 * MB);  // 2 MB  [m][d]
  float*          P  = (float*)(ws + 16 * MB);           // 16 MB (4 partials)
  unsigned short* Xb = (unsigned short*)(ws + 32 * MB);  // 16 MB

  build_G_kernel<<<DD, 256, 0, stream>>>(wrp, wip, Gf);
  transpose_G_kernel<<<dim3(16, 16), 256, 0, stream>>>(Gf, Gt);
  // P[z] = Gt . B(twiddles)^T (256 MFMA blocks) + Xb = bf16(x) (4096 blocks)
  build_M_convert_kernel<<<4352, 256, 0, stream>>>(Gt, P, x, Xb);
  reduce_M_kernel<<<DD, 256, 0, stream>>>(P, Mb);
  // Y = Xb . Mb^T + bias   (XCD-chunk swizzled 1-D grid)
  gemm_y_kernel<<<512, 256, 0, stream>>>(Xb, Mb, bias, y);
}